// Round 3
// baseline (210.872 us; speedup 1.0000x reference)
//
#include <hip/hip_runtime.h>

// IndependentMLP: x(4096,1024), w0(1024,1,16), w1(1024,16,16), wf(1024,16,8)
// out[b,i,j] = sum_k tanh( sum_l tanh(x[b,i]*w0[i,l]) * w1[i,l,k] ) * wf[i,k,j]
//
// Per-i tiny GEMMs on v_mfma_f32_16x16x16f16, computed TRANSPOSED so MFMA1's
// C/D layout == MFMA2's B layout (no shuffle between layers):
//   MFMA1: A = w1^T frag, B = h1^T frag  -> D1[n=h2idx][m=batch]
//   MFMA2: A = wf^T frag, B = tanh(D1)   -> D2[j=outcol][m=batch]
// D2 lane (g<2, r) holds out[b0+r][i][4g..4g+3] = one aligned float4 -> store
// DIRECTLY to global. No LDS, no barriers, and NO WORKSPACE: the harness
// re-poisons d_ws (512 MiB, ~78 us at 85% HBM peak) inside the timed region,
// which dwarfs the coalescing benefit of a transposed-x staging pass. x is
// 16 MiB -> L2-resident; the strided per-lane read mostly hits L2.
// w0/w1 fragments are pre-scaled by 2*log2(e) so tanh skips one multiply.

typedef _Float16 half4 __attribute__((ext_vector_type(4)));
typedef float f32x4 __attribute__((ext_vector_type(4)));

#define TANH_SCALE 2.885390081777927f  // 2*log2(e)

__device__ __forceinline__ float tanh_pre(float y) {
  // y = 2*log2e*x ; tanh(x) = 1 - 2/(exp2(y)+1); inf/0 endpoints -> +-1.
  float e = __builtin_amdgcn_exp2f(y);
  return 1.0f - 2.0f * __builtin_amdgcn_rcpf(e + 1.0f);
}

__global__ __launch_bounds__(256, 8) void mlp_main(const float* __restrict__ x,
                                                   const float* __restrict__ w0,
                                                   const float* __restrict__ w1,
                                                   const float* __restrict__ wf,
                                                   float* __restrict__ out) {
  const int tid = threadIdx.x;
  const int wid = tid >> 6;    // wave 0..3 -> i offset
  const int lane = tid & 63;
  const int g = lane >> 4;     // 0..3 (k-group)
  const int r = lane & 15;     // m / n / j slot
  const int ig = blockIdx.x & 255;  // i-group (4 i's)
  const int bs = blockIdx.x >> 8;   // batch split 0..7
  const int i = ig * 4 + wid;
  const int bbase = bs * 512;

  // A1 = w1^T fragment: element [row=n=r][k=4g+ii] = w1[i][4g+ii][r],
  // pre-scaled by 2*log2e so tanh(D1) needs no multiply.
  half4 aw1;
  {
    const float* w1p = w1 + i * 256 + g * 64 + r;
#pragma unroll
    for (int ii = 0; ii < 4; ++ii) aw1[ii] = (_Float16)(w1p[ii * 16] * TANH_SCALE);
  }
  // A2 = wf^T fragment: [row=j=r][k2=4g+ii] = wf[i][4g+ii][r], zero for r>=8
  half4 awf;
  {
    const float* wfp = wf + i * 128 + g * 32 + r;
#pragma unroll
    for (int ii = 0; ii < 4; ++ii)
      awf[ii] = (r < 8) ? (_Float16)wfp[ii * 8] : (_Float16)0.0f;
  }
  // w0, pre-scaled likewise.
  float w0g[4];
  {
    const float4 v = *(const float4*)(w0 + i * 16 + g * 4);
    w0g[0] = v.x * TANH_SCALE; w0g[1] = v.y * TANH_SCALE;
    w0g[2] = v.z * TANH_SCALE; w0g[3] = v.w * TANH_SCALE;
  }

  // x pointer: lane r reads batch row b0+r, column i (broadcast across g).
  // Strided (4 KB between lanes) but x is L2-resident after first touch.
  const float* xp = x + (size_t)(bbase + r) * 1024 + i;

  // Direct store base: lane (g<2, r) owns out[bbase+r][i][4g..4g+3].
  float* op = out + (size_t)(bbase + r) * 8192 + i * 8 + g * 4;

  const f32x4 zero = {0.f, 0.f, 0.f, 0.f};

  float xv = xp[0];
  for (int t = 0; t < 32; ++t) {
    // h1^T fragment (B1): [k=4g+ii][m=r] = tanh(x[b0+r]*w0[i][4g+ii])
    half4 bh1;
#pragma unroll
    for (int ii = 0; ii < 4; ++ii) bh1[ii] = (_Float16)tanh_pre(xv * w0g[ii]);
    // prefetch next tile's x early
    if (t < 31) xv = xp[(size_t)(t + 1) * 16 * 1024];

    // D1 = w1^T @ h1^T : lane reg ii holds (2log2e)*preact2[n=4g+ii][m=r]
    f32x4 d1 = __builtin_amdgcn_mfma_f32_16x16x16f16(aw1, bh1, zero, 0, 0, 0);
    // h2^T fragment (B2) = tanh(D1) in-place: [k2=4g+ii][m=r]
    half4 bh2;
#pragma unroll
    for (int ii = 0; ii < 4; ++ii) bh2[ii] = (_Float16)tanh_pre(d1[ii]);
    // D2 = wf^T @ h2^T : lane reg ii holds out[j=4g+ii][m=r] (valid j<8 -> g<2)
    f32x4 d2 = __builtin_amdgcn_mfma_f32_16x16x16f16(awf, bh2, zero, 0, 0, 0);

    // Direct float4 store: 4 consecutive j for batch row b0+r.
    if (g < 2) *(f32x4*)(op + (size_t)t * 16 * 8192) = d2;
  }
}

extern "C" void kernel_launch(void* const* d_in, const int* in_sizes, int n_in,
                              void* d_out, int out_size, void* d_ws, size_t ws_size,
                              hipStream_t stream) {
  const float* x = (const float*)d_in[0];
  const float* w0 = (const float*)d_in[1];
  const float* w1 = (const float*)d_in[2];
  const float* wf = (const float*)d_in[3];
  float* out = (float*)d_out;
  (void)d_ws; (void)ws_size;  // deliberately unused: avoids 512 MiB re-poison cost

  mlp_main<<<2048, 256, 0, stream>>>(x, w0, w1, wf, out);
}

// Round 4
// 166.317 us; speedup vs baseline: 1.2679x; 1.2679x over previous
//
#include <hip/hip_runtime.h>

// IndependentMLP: x(4096,1024), w0(1024,1,16), w1(1024,16,16), wf(1024,16,8)
// out[b,i,j] = sum_k tanh( sum_l tanh(x[b,i]*w0[i,l]) * w1[i,l,k] ) * wf[i,k,j]
//
// Per-i tiny GEMMs on v_mfma_f32_16x16x16f16, computed TRANSPOSED so MFMA1's
// C/D layout == MFMA2's B layout (no shuffle between layers):
//   MFMA1: A = w1^T frag, B = h1^T frag  -> D1[n=h2idx][m=batch]
//   MFMA2: A = wf^T frag, B = tanh(D1)   -> D2[j=outcol][m=batch]
// D2 lane (g<2, r) holds out[b0+r][i][4g..4g+3] = one aligned float4 -> store
// DIRECTLY to global. No LDS, no barriers.
//
// Harness note (r3 evidence): the 512 MiB d_ws poison fill runs UNCONDITIONALLY
// (~78 us) whether or not we use d_ws, so the transpose staging pass is free
// at the margin and saves 4x x-read over-fetch (FETCH 68 MB -> 17 MB ideal).
//
// r3 counters (MfmaUtil 3.4%, VALUBusy 24.5%, HBM 28%) = latency-bound: the
// per-iter chain tanh->MFMA1->tanh->MFMA2 (~125 cy) is unhidden. This version
// processes TWO independent batch-tiles per iteration, interleaved, to double
// the ILP in the chain's shadow. w0/w1 pre-scaled by 2*log2e.

typedef _Float16 half4 __attribute__((ext_vector_type(4)));
typedef float f32x4 __attribute__((ext_vector_type(4)));

#define TANH_SCALE 2.885390081777927f  // 2*log2(e)

__device__ __forceinline__ float tanh_pre(float y) {
  // y = 2*log2e*x ; tanh(x) = 1 - 2/(exp2(y)+1); inf/0 endpoints -> +-1.
  float e = __builtin_amdgcn_exp2f(y);
  return 1.0f - 2.0f * __builtin_amdgcn_rcpf(e + 1.0f);
}

// x (4096 x 1024) -> xT (1024 x 4096), 64x64 LDS tiles, fully coalesced.
__global__ __launch_bounds__(256) void transpose_x(const float* __restrict__ src,
                                                   float* __restrict__ dst) {
  __shared__ float tile[64][65];
  const int t = threadIdx.x;
  const int bx = blockIdx.x & 15;   // 1024/64 col tiles
  const int by = blockIdx.x >> 4;   // 4096/64 row tiles
  const int c0 = bx * 64, r0 = by * 64;
  const int tr = t >> 4;            // 0..15
  const int tc = (t & 15) * 4;      // 0..60
#pragma unroll
  for (int q = 0; q < 4; ++q) {
    const float4 v = *(const float4*)(src + (size_t)(r0 + tr + q * 16) * 1024 + c0 + tc);
    tile[tr + q * 16][tc + 0] = v.x;
    tile[tr + q * 16][tc + 1] = v.y;
    tile[tr + q * 16][tc + 2] = v.z;
    tile[tr + q * 16][tc + 3] = v.w;
  }
  __syncthreads();
#pragma unroll
  for (int q = 0; q < 4; ++q) {
    const int c = tr + q * 16;
    float4 v;
    v.x = tile[tc + 0][c];
    v.y = tile[tc + 1][c];
    v.z = tile[tc + 2][c];
    v.w = tile[tc + 3][c];
    *(float4*)(dst + (size_t)(c0 + c) * 4096 + r0 + tc) = v;
  }
}

__global__ __launch_bounds__(256, 8) void mlp_main(const float* __restrict__ xsrc,
                                                   const float* __restrict__ w0,
                                                   const float* __restrict__ w1,
                                                   const float* __restrict__ wf,
                                                   float* __restrict__ out,
                                                   int transposed) {
  const int tid = threadIdx.x;
  const int wid = tid >> 6;    // wave 0..3 -> i offset
  const int lane = tid & 63;
  const int g = lane >> 4;     // 0..3 (k-group)
  const int r = lane & 15;     // m / n / j slot
  const int ig = blockIdx.x & 255;  // i-group (4 i's)
  const int bs = blockIdx.x >> 8;   // batch split 0..7
  const int i = ig * 4 + wid;
  const int bbase = bs * 512;

  // A1 = w1^T fragment: element [row=n=r][k=4g+ii] = w1[i][4g+ii][r],
  // pre-scaled by 2*log2e so tanh(D1) needs no multiply.
  half4 aw1;
  {
    const float* w1p = w1 + i * 256 + g * 64 + r;
#pragma unroll
    for (int ii = 0; ii < 4; ++ii) aw1[ii] = (_Float16)(w1p[ii * 16] * TANH_SCALE);
  }
  // A2 = wf^T fragment: [row=j=r][k2=4g+ii] = wf[i][4g+ii][r], zero for r>=8
  half4 awf;
  {
    const float* wfp = wf + i * 128 + g * 32 + r;
#pragma unroll
    for (int ii = 0; ii < 4; ++ii)
      awf[ii] = (r < 8) ? (_Float16)wfp[ii * 8] : (_Float16)0.0f;
  }
  // w0, pre-scaled likewise.
  float w0g[4];
  {
    const float4 v = *(const float4*)(w0 + i * 16 + g * 4);
    w0g[0] = v.x * TANH_SCALE; w0g[1] = v.y * TANH_SCALE;
    w0g[2] = v.z * TANH_SCALE; w0g[3] = v.w * TANH_SCALE;
  }

  // x pointer: lane r reads batch row b0+r (broadcast across g-groups)
  const float* xp = transposed ? xsrc + (size_t)i * 4096 + bbase + r
                               : xsrc + (size_t)(bbase + r) * 1024 + i;
  const size_t xstep = transposed ? 16u : 16u * 1024u;

  // Direct store base: lane (g<2, r) owns out[bbase+r][i][4g..4g+3].
  float* op = out + (size_t)(bbase + r) * 8192 + i * 8 + g * 4;

  const f32x4 zero = {0.f, 0.f, 0.f, 0.f};

  // Two independent batch-tiles in flight per iteration.
  float xva = xp[0];
  float xvb = xp[xstep];
  for (int t = 0; t < 32; t += 2) {
    // h1^T fragments for both tiles
    half4 bh1a, bh1b;
#pragma unroll
    for (int ii = 0; ii < 4; ++ii) bh1a[ii] = (_Float16)tanh_pre(xva * w0g[ii]);
#pragma unroll
    for (int ii = 0; ii < 4; ++ii) bh1b[ii] = (_Float16)tanh_pre(xvb * w0g[ii]);
    // prefetch next pair early (2-deep)
    if (t < 30) {
      xva = xp[(size_t)(t + 2) * xstep];
      xvb = xp[(size_t)(t + 3) * xstep];
    }

    // Layer-2 preacts, both tiles (independent MFMA chains)
    f32x4 d1a = __builtin_amdgcn_mfma_f32_16x16x16f16(aw1, bh1a, zero, 0, 0, 0);
    f32x4 d1b = __builtin_amdgcn_mfma_f32_16x16x16f16(aw1, bh1b, zero, 0, 0, 0);

    half4 bh2a, bh2b;
#pragma unroll
    for (int ii = 0; ii < 4; ++ii) bh2a[ii] = (_Float16)tanh_pre(d1a[ii]);
#pragma unroll
    for (int ii = 0; ii < 4; ++ii) bh2b[ii] = (_Float16)tanh_pre(d1b[ii]);

    f32x4 d2a = __builtin_amdgcn_mfma_f32_16x16x16f16(awf, bh2a, zero, 0, 0, 0);
    f32x4 d2b = __builtin_amdgcn_mfma_f32_16x16x16f16(awf, bh2b, zero, 0, 0, 0);

    // Direct float4 stores: 4 consecutive j for batch rows b0+r, b0+16+r.
    if (g < 2) {
      *(f32x4*)(op + (size_t)t * 16 * 8192) = d2a;
      *(f32x4*)(op + (size_t)(t + 1) * 16 * 8192) = d2b;
    }
  }
}

extern "C" void kernel_launch(void* const* d_in, const int* in_sizes, int n_in,
                              void* d_out, int out_size, void* d_ws, size_t ws_size,
                              hipStream_t stream) {
  const float* x = (const float*)d_in[0];
  const float* w0 = (const float*)d_in[1];
  const float* w1 = (const float*)d_in[2];
  const float* wf = (const float*)d_in[3];
  float* out = (float*)d_out;
  float* xT = (float*)d_ws;

  const size_t xT_bytes = (size_t)1024 * 4096 * sizeof(float);
  const bool useT = ws_size >= xT_bytes;
  if (useT) {
    transpose_x<<<1024, 256, 0, stream>>>(x, xT);
    mlp_main<<<2048, 256, 0, stream>>>(xT, w0, w1, wf, out, 1);
  } else {
    mlp_main<<<2048, 256, 0, stream>>>(x, w0, w1, wf, out, 0);
  }
}

// Round 5
// 162.403 us; speedup vs baseline: 1.2984x; 1.0241x over previous
//
#include <hip/hip_runtime.h>

// IndependentMLP: x(4096,1024), w0(1024,1,16), w1(1024,16,16), wf(1024,16,8)
// out[b,i,j] = sum_k tanh( sum_l tanh(x[b,i]*w0[i,l]) * w1[i,l,k] ) * wf[i,k,j]
//
// Per-i tiny GEMMs on v_mfma_f32_16x16x16f16, computed TRANSPOSED so MFMA1's
// C/D layout == MFMA2's B layout (no shuffle between layers):
//   MFMA1: A = w1^T frag, B = h1^T frag  -> D1[n=h2idx][m=batch]
//   MFMA2: A = wf^T frag, B = tanh(D1)   -> D2[j=outcol][m=batch]
// D2 lane (g<2, r) holds out[b0+r][i][4g..4g+3] = one aligned float4 -> store
// DIRECTLY to global. No LDS, no barriers.
//
// Harness facts (r3/r4 evidence):
//  - the 512 MiB d_ws poison fill runs UNCONDITIONALLY (~78 us) -> the
//    transpose staging pass is free at the margin; it saves 4x x over-fetch
//    (FETCH 68 MB -> 17 MB) and ~50 us of mlp_main time (r3: 95.5 us strided).
//  - r4 (2-way ILP, 1-iter prefetch) ~= r2 (no ILP): the binder is x-load
//    LATENCY (~600-900 cy L3/HBM) vs ~200-400 cy prefetch distance, not ILP.
//    VALUBusy 24.5% / MfmaUtil 3.4% = classic latency-bound signature.
// This version issues ALL 32 x-loads up front into two statically-indexed
// 16-float register arrays (no runtime indexing -> no scratch), then runs the
// 32 tiles with no load stalls after the initial drain. w0/w1 pre-scaled by
// 2*log2e so tanh skips one multiply.

typedef _Float16 half4 __attribute__((ext_vector_type(4)));
typedef float f32x4 __attribute__((ext_vector_type(4)));

#define TANH_SCALE 2.885390081777927f  // 2*log2(e)

__device__ __forceinline__ float tanh_pre(float y) {
  // y = 2*log2e*x ; tanh(x) = 1 - 2/(exp2(y)+1); inf/0 endpoints -> +-1.
  float e = __builtin_amdgcn_exp2f(y);
  return 1.0f - 2.0f * __builtin_amdgcn_rcpf(e + 1.0f);
}

// x (4096 x 1024) -> xT (1024 x 4096), 64x64 LDS tiles, fully coalesced.
__global__ __launch_bounds__(256) void transpose_x(const float* __restrict__ src,
                                                   float* __restrict__ dst) {
  __shared__ float tile[64][65];
  const int t = threadIdx.x;
  const int bx = blockIdx.x & 15;   // 1024/64 col tiles
  const int by = blockIdx.x >> 4;   // 4096/64 row tiles
  const int c0 = bx * 64, r0 = by * 64;
  const int tr = t >> 4;            // 0..15
  const int tc = (t & 15) * 4;      // 0..60
#pragma unroll
  for (int q = 0; q < 4; ++q) {
    const float4 v = *(const float4*)(src + (size_t)(r0 + tr + q * 16) * 1024 + c0 + tc);
    tile[tr + q * 16][tc + 0] = v.x;
    tile[tr + q * 16][tc + 1] = v.y;
    tile[tr + q * 16][tc + 2] = v.z;
    tile[tr + q * 16][tc + 3] = v.w;
  }
  __syncthreads();
#pragma unroll
  for (int q = 0; q < 4; ++q) {
    const int c = tr + q * 16;
    float4 v;
    v.x = tile[tc + 0][c];
    v.y = tile[tc + 1][c];
    v.z = tile[tc + 2][c];
    v.w = tile[tc + 3][c];
    *(float4*)(dst + (size_t)(c0 + c) * 4096 + r0 + tc) = v;
  }
}

__global__ __launch_bounds__(256, 8) void mlp_main(const float* __restrict__ xsrc,
                                                   const float* __restrict__ w0,
                                                   const float* __restrict__ w1,
                                                   const float* __restrict__ wf,
                                                   float* __restrict__ out,
                                                   int transposed) {
  const int tid = threadIdx.x;
  const int wid = tid >> 6;    // wave 0..3 -> i offset
  const int lane = tid & 63;
  const int g = lane >> 4;     // 0..3 (k-group)
  const int r = lane & 15;     // m / n / j slot
  const int ig = blockIdx.x & 255;  // i-group (4 i's)
  const int bs = blockIdx.x >> 8;   // batch split 0..7
  const int i = ig * 4 + wid;
  const int bbase = bs * 512;

  // x pointer: lane r reads batch row b0+r (broadcast across g-groups)
  const float* xp = transposed ? xsrc + (size_t)i * 4096 + bbase + r
                               : xsrc + (size_t)(bbase + r) * 1024 + i;
  const size_t xstep = transposed ? 16u : 16u * 1024u;

  // Issue ALL 32 x loads up front (statically indexed -> stays in VGPRs).
  // Prefetch distance >> load latency; waves never stall on x after drain.
  float xa[16], xb[16];
#pragma unroll
  for (int d = 0; d < 16; ++d) xa[d] = xp[(size_t)d * xstep];
#pragma unroll
  for (int d = 0; d < 16; ++d) xb[d] = xp[(size_t)(d + 16) * xstep];

  // A1 = w1^T fragment: element [row=n=r][k=4g+ii] = w1[i][4g+ii][r],
  // pre-scaled by 2*log2e so tanh(D1) needs no multiply.
  half4 aw1;
  {
    const float* w1p = w1 + i * 256 + g * 64 + r;
#pragma unroll
    for (int ii = 0; ii < 4; ++ii) aw1[ii] = (_Float16)(w1p[ii * 16] * TANH_SCALE);
  }
  // A2 = wf^T fragment: [row=j=r][k2=4g+ii] = wf[i][4g+ii][r], zero for r>=8
  half4 awf;
  {
    const float* wfp = wf + i * 128 + g * 32 + r;
#pragma unroll
    for (int ii = 0; ii < 4; ++ii)
      awf[ii] = (r < 8) ? (_Float16)wfp[ii * 8] : (_Float16)0.0f;
  }
  // w0, pre-scaled likewise.
  float w0g[4];
  {
    const float4 v = *(const float4*)(w0 + i * 16 + g * 4);
    w0g[0] = v.x * TANH_SCALE; w0g[1] = v.y * TANH_SCALE;
    w0g[2] = v.z * TANH_SCALE; w0g[3] = v.w * TANH_SCALE;
  }

  // Direct store base: lane (g<2, r) owns out[bbase+r][i][4g..4g+3].
  float* op = out + (size_t)(bbase + r) * 8192 + i * 8 + g * 4;

  const f32x4 zero = {0.f, 0.f, 0.f, 0.f};

  // Two independent batch-tiles per step for ILP in the tanh->MFMA chain.
  auto tile2 = [&](float xva, float xvb, int t) {
    half4 bh1a, bh1b;
#pragma unroll
    for (int ii = 0; ii < 4; ++ii) bh1a[ii] = (_Float16)tanh_pre(xva * w0g[ii]);
#pragma unroll
    for (int ii = 0; ii < 4; ++ii) bh1b[ii] = (_Float16)tanh_pre(xvb * w0g[ii]);

    f32x4 d1a = __builtin_amdgcn_mfma_f32_16x16x16f16(aw1, bh1a, zero, 0, 0, 0);
    f32x4 d1b = __builtin_amdgcn_mfma_f32_16x16x16f16(aw1, bh1b, zero, 0, 0, 0);

    half4 bh2a, bh2b;
#pragma unroll
    for (int ii = 0; ii < 4; ++ii) bh2a[ii] = (_Float16)tanh_pre(d1a[ii]);
#pragma unroll
    for (int ii = 0; ii < 4; ++ii) bh2b[ii] = (_Float16)tanh_pre(d1b[ii]);

    f32x4 d2a = __builtin_amdgcn_mfma_f32_16x16x16f16(awf, bh2a, zero, 0, 0, 0);
    f32x4 d2b = __builtin_amdgcn_mfma_f32_16x16x16f16(awf, bh2b, zero, 0, 0, 0);

    if (g < 2) {
      *(f32x4*)(op + (size_t)t * 16 * 8192) = d2a;
      *(f32x4*)(op + (size_t)(t + 1) * 16 * 8192) = d2b;
    }
  };

#pragma unroll
  for (int t = 0; t < 16; t += 2) tile2(xa[t], xa[t + 1], t);
#pragma unroll
  for (int t = 0; t < 16; t += 2) tile2(xb[t], xb[t + 1], t + 16);
}

extern "C" void kernel_launch(void* const* d_in, const int* in_sizes, int n_in,
                              void* d_out, int out_size, void* d_ws, size_t ws_size,
                              hipStream_t stream) {
  const float* x = (const float*)d_in[0];
  const float* w0 = (const float*)d_in[1];
  const float* w1 = (const float*)d_in[2];
  const float* wf = (const float*)d_in[3];
  float* out = (float*)d_out;
  float* xT = (float*)d_ws;

  const size_t xT_bytes = (size_t)1024 * 4096 * sizeof(float);
  const bool useT = ws_size >= xT_bytes;
  if (useT) {
    transpose_x<<<1024, 256, 0, stream>>>(x, xT);
    mlp_main<<<2048, 256, 0, stream>>>(xT, w0, w1, wf, out, 1);
  } else {
    mlp_main<<<2048, 256, 0, stream>>>(x, w0, w1, wf, out, 0);
  }
}

// Round 6
// 158.100 us; speedup vs baseline: 1.3338x; 1.0272x over previous
//
#include <hip/hip_runtime.h>

// IndependentMLP: x(4096,1024), w0(1024,1,16), w1(1024,16,16), wf(1024,16,8)
// out[b,i,j] = sum_k tanh( sum_l tanh(x[b,i]*w0[i,l]) * w1[i,l,k] ) * wf[i,k,j]
//
// FUSED single kernel (r5 evidence): separate transpose_x + mlp paid 34 MB
// extra HBM traffic + 6 us dispatch; the block only needs a 512x16 slice of x.
// Block = 1024 thr = 16 waves; wave w owns i = ig*16+w. Stage
// x[bbase:+512][i0:+16] into LDS ONCE (fully coalesced: 16 consecutive
// i-columns = 64 B/row segment, every line fully used -> FETCH ~17 MB ideal),
// then 32 batch-tiles of per-i tiny GEMMs on v_mfma_f32_16x16x16f16, computed
// TRANSPOSED so MFMA1's C/D layout == MFMA2's B layout:
//   MFMA1: A = w1^T frag, B = h1^T frag  -> D1[n=h2idx][m=batch]
//   MFMA2: A = wf^T frag, B = tanh(D1)   -> D2[j=outcol][m=batch]
// D2 lane (g<2, r) holds out[b0+r][i][4g..4g+3] -> direct float4 store.
// LDS pitch 17: read banks (17*r + const) mod 32 are 16 distinct for r=0..15,
// broadcast across g-groups -> conflict-free. w0/w1 pre-scaled by 2*log2e.
//
// Harness facts: 512 MiB d_ws poison (~78 us) + out poison run UNCONDITIONALLY
// (r3: C ~= 115 us fixed); only the ~47 us kernel region is controllable.

typedef _Float16 half4 __attribute__((ext_vector_type(4)));
typedef float f32x4 __attribute__((ext_vector_type(4)));

#define TANH_SCALE 2.885390081777927f  // 2*log2(e)
#define XPITCH 17

__device__ __forceinline__ float tanh_pre(float y) {
  // y = 2*log2e*x ; tanh(x) = 1 - 2/(exp2(y)+1); inf/0 endpoints -> +-1.
  float e = __builtin_amdgcn_exp2f(y);
  return 1.0f - 2.0f * __builtin_amdgcn_rcpf(e + 1.0f);
}

__global__ __launch_bounds__(1024, 8) void mlp_fused(const float* __restrict__ x,
                                                     const float* __restrict__ w0,
                                                     const float* __restrict__ w1,
                                                     const float* __restrict__ wf,
                                                     float* __restrict__ out) {
  __shared__ float xs[512 * XPITCH];  // 34816 B -> 2 blocks/CU

  const int tid = threadIdx.x;
  const int wid = tid >> 6;         // wave 0..15 -> i offset
  const int lane = tid & 63;
  const int g = lane >> 4;          // 0..3 (k-group)
  const int r = lane & 15;          // m / n / j slot
  const int ig = blockIdx.x & 63;   // 64 i-groups of 16
  const int bs = blockIdx.x >> 6;   // 8 batch splits of 512
  const int i = ig * 16 + wid;
  const int bbase = bs * 512;

  // ---- stage x slice into LDS: 1024 thr x 2 float4 = 512 rows x 16 cols ----
  {
    const int rr = tid >> 2;        // 0..255
    const int c4 = (tid & 3) * 4;   // 0,4,8,12
#pragma unroll
    for (int p = 0; p < 2; ++p) {
      const int row = p * 256 + rr;
      const float4 v =
          *(const float4*)(x + (size_t)(bbase + row) * 1024 + ig * 16 + c4);
      float* d = &xs[row * XPITCH + c4];
      d[0] = v.x; d[1] = v.y; d[2] = v.z; d[3] = v.w;
    }
  }

  // A1 = w1^T fragment: [row=n=r][k=4g+ii] = w1[i][4g+ii][r], pre-scaled.
  half4 aw1;
  {
    const float* w1p = w1 + i * 256 + g * 64 + r;
#pragma unroll
    for (int ii = 0; ii < 4; ++ii) aw1[ii] = (_Float16)(w1p[ii * 16] * TANH_SCALE);
  }
  // A2 = wf^T fragment: [row=j=r][k2=4g+ii] = wf[i][4g+ii][r], zero for r>=8.
  half4 awf;
  {
    const float* wfp = wf + i * 128 + g * 32 + r;
#pragma unroll
    for (int ii = 0; ii < 4; ++ii)
      awf[ii] = (r < 8) ? (_Float16)wfp[ii * 8] : (_Float16)0.0f;
  }
  // w0, pre-scaled likewise.
  float w0g[4];
  {
    const float4 v = *(const float4*)(w0 + i * 16 + g * 4);
    w0g[0] = v.x * TANH_SCALE; w0g[1] = v.y * TANH_SCALE;
    w0g[2] = v.z * TANH_SCALE; w0g[3] = v.w * TANH_SCALE;
  }

  __syncthreads();

  // Direct store base: lane (g<2, r) owns out[bbase+r][i][4g..4g+3].
  float* op = out + (size_t)(bbase + r) * 8192 + i * 8 + g * 4;
  // LDS read base: lane r reads xs[(t*16+r)*17 + wid] (broadcast across g).
  const float* xr = &xs[r * XPITCH + wid];

  const f32x4 zero = {0.f, 0.f, 0.f, 0.f};

#pragma unroll
  for (int t = 0; t < 32; t += 2) {
    const float xva = xr[(size_t)t * 16 * XPITCH];
    const float xvb = xr[(size_t)(t + 1) * 16 * XPITCH];

    half4 bh1a, bh1b;
#pragma unroll
    for (int ii = 0; ii < 4; ++ii) bh1a[ii] = (_Float16)tanh_pre(xva * w0g[ii]);
#pragma unroll
    for (int ii = 0; ii < 4; ++ii) bh1b[ii] = (_Float16)tanh_pre(xvb * w0g[ii]);

    f32x4 d1a = __builtin_amdgcn_mfma_f32_16x16x16f16(aw1, bh1a, zero, 0, 0, 0);
    f32x4 d1b = __builtin_amdgcn_mfma_f32_16x16x16f16(aw1, bh1b, zero, 0, 0, 0);

    half4 bh2a, bh2b;
#pragma unroll
    for (int ii = 0; ii < 4; ++ii) bh2a[ii] = (_Float16)tanh_pre(d1a[ii]);
#pragma unroll
    for (int ii = 0; ii < 4; ++ii) bh2b[ii] = (_Float16)tanh_pre(d1b[ii]);

    f32x4 d2a = __builtin_amdgcn_mfma_f32_16x16x16f16(awf, bh2a, zero, 0, 0, 0);
    f32x4 d2b = __builtin_amdgcn_mfma_f32_16x16x16f16(awf, bh2b, zero, 0, 0, 0);

    if (g < 2) {
      *(f32x4*)(op + (size_t)t * 16 * 8192) = d2a;
      *(f32x4*)(op + (size_t)(t + 1) * 16 * 8192) = d2b;
    }
  }
}

extern "C" void kernel_launch(void* const* d_in, const int* in_sizes, int n_in,
                              void* d_out, int out_size, void* d_ws, size_t ws_size,
                              hipStream_t stream) {
  const float* x = (const float*)d_in[0];
  const float* w0 = (const float*)d_in[1];
  const float* w1 = (const float*)d_in[2];
  const float* wf = (const float*)d_in[3];
  float* out = (float*)d_out;
  (void)d_ws; (void)ws_size;  // workspace poison is unconditional; ws unused

  mlp_fused<<<512, 1024, 0, stream>>>(x, w0, w1, wf, out);
}